// Round 1
// baseline (595.792 us; speedup 1.0000x reference)
//
#include <hip/hip_runtime.h>

// MultiheadAttention: B=4, S=2048, D_MODEL=1024, H=16, D_K=64, fp32 in/out.
// Pipeline (all bf16 MFMA 16x16x32, fp32 accum):
//   1. transpose_w x4: W[K][N] f32 -> Wt[N][K] bf16
//   2. gemm<1,0>: Q = (q@wq+bq)*0.125 -> bf16 [8192][1024]
//   3. gemm<1,0>: K = k@wk+bk        -> bf16 [8192][1024]
//   4. gemm<1,2>: V = v@wv+bv        -> bf16 transposed [b,h,d,s]
//   5. attn: flash-style online softmax, P via LDS roundtrip -> Cv bf16
//   6. gemm<0,1>: out = Cv@wo+bo -> f32 d_out

#define DM 1024
#define SQL 2048

typedef __attribute__((ext_vector_type(4))) float floatx4;
typedef __attribute__((ext_vector_type(8))) __bf16 bf16x8;

__device__ __forceinline__ unsigned short f2bf(float f) {
  unsigned int u = __float_as_uint(f);
  u += 0x7fffu + ((u >> 16) & 1u);   // RNE
  return (unsigned short)(u >> 16);
}

// ---------------- weight transpose: W[1024][1024] f32 -> Wt[1024][1024] bf16 (Wt[n][k]=W[k][n])
__global__ __launch_bounds__(256) void transpose_w_kernel(
    const float* __restrict__ W, unsigned short* __restrict__ Wt) {
  __shared__ unsigned short t[64][65];
  int tid = threadIdx.x;
  int n0 = blockIdx.x * 64, k0 = blockIdx.y * 64;
  for (int u = 0; u < 16; u++) {
    int idx = u * 256 + tid;
    int k = idx >> 6, n = idx & 63;
    t[k][n] = f2bf(W[(size_t)(k0 + k) * DM + n0 + n]);
  }
  __syncthreads();
  for (int u = 0; u < 16; u++) {
    int idx = u * 256 + tid;
    int n = idx >> 6, k = idx & 63;
    Wt[(size_t)(n0 + n) * DM + k0 + k] = t[k][n];
  }
}

// ---------------- GEMM: Out[8192][1024] = A[8192][1024] @ Wt^T + bias, tile 128x128, BK=64
// A_F32: A is f32 (else bf16). OUT_MODE: 0=bf16 row-major, 1=f32 row-major, 2=bf16 V-transposed [b,h,d,s]
template <int A_F32, int OUT_MODE>
__global__ __launch_bounds__(256) void gemm_kernel(
    const void* __restrict__ Ap, const unsigned short* __restrict__ Bt,
    const float* __restrict__ bias, void* __restrict__ Outp, float out_scale) {
  __shared__ unsigned short lds_a[128 * 72];  // [128][64] data, stride 72 (144B rows, 16B aligned)
  __shared__ unsigned short lds_b[128 * 72];
  int tid = threadIdx.x;
  int wave = tid >> 6, lane = tid & 63;
  int quad = lane >> 4, c16 = lane & 15;
  int wm = wave & 1, wn = wave >> 1;
  int m0 = blockIdx.y * 128, n0 = blockIdx.x * 128;

  floatx4 acc[4][4];
  const floatx4 fzero = {0.f, 0.f, 0.f, 0.f};
  for (int i = 0; i < 4; i++)
    for (int j = 0; j < 4; j++) acc[i][j] = fzero;

  for (int kt = 0; kt < DM; kt += 64) {
    if (A_F32) {
      const float* A = (const float*)Ap;
      for (int u = 0; u < 8; u++) {
        int idx = u * 256 + tid;           // 2048 float4-chunks, 16/row
        int r = idx >> 4, c4 = idx & 15;
        float4 v = *(const float4*)&A[(size_t)(m0 + r) * DM + kt + c4 * 4];
        uint2 pk;
        pk.x = (unsigned)f2bf(v.x) | ((unsigned)f2bf(v.y) << 16);
        pk.y = (unsigned)f2bf(v.z) | ((unsigned)f2bf(v.w) << 16);
        *(uint2*)&lds_a[r * 72 + c4 * 4] = pk;
      }
    } else {
      const unsigned short* A = (const unsigned short*)Ap;
      for (int u = 0; u < 4; u++) {
        int idx = u * 256 + tid;           // 1024 8-half chunks, 8/row
        int r = idx >> 3, c8 = idx & 7;
        *(uint4*)&lds_a[r * 72 + c8 * 8] =
            *(const uint4*)&A[(size_t)(m0 + r) * DM + kt + c8 * 8];
      }
    }
    for (int u = 0; u < 4; u++) {
      int idx = u * 256 + tid;
      int r = idx >> 3, c8 = idx & 7;
      *(uint4*)&lds_b[r * 72 + c8 * 8] =
          *(const uint4*)&Bt[(size_t)(n0 + r) * DM + kt + c8 * 8];
    }
    __syncthreads();
    for (int ks = 0; ks < 2; ks++) {
      bf16x8 af[4], bfr[4];
      for (int i = 0; i < 4; i++)
        af[i] = *(const bf16x8*)&lds_a[(wm * 64 + i * 16 + c16) * 72 + ks * 32 + quad * 8];
      for (int j = 0; j < 4; j++)
        bfr[j] = *(const bf16x8*)&lds_b[(wn * 64 + j * 16 + c16) * 72 + ks * 32 + quad * 8];
      for (int i = 0; i < 4; i++)
        for (int j = 0; j < 4; j++)
          acc[i][j] = __builtin_amdgcn_mfma_f32_16x16x32_bf16(af[i], bfr[j], acc[i][j], 0, 0, 0);
    }
    __syncthreads();
  }

  // epilogue: C/D layout row=(lane>>4)*4+reg, col=lane&15
  for (int i = 0; i < 4; i++)
    for (int j = 0; j < 4; j++) {
      int gc = n0 + wn * 64 + j * 16 + c16;
      float bv = bias[gc];
      float val[4];
      for (int r = 0; r < 4; r++) val[r] = (acc[i][j][r] + bv) * out_scale;
      int gr0 = m0 + wm * 64 + i * 16 + quad * 4;
      if (OUT_MODE == 1) {
        float* O = (float*)Outp;
        for (int r = 0; r < 4; r++) O[(size_t)(gr0 + r) * DM + gc] = val[r];
      } else if (OUT_MODE == 0) {
        unsigned short* O = (unsigned short*)Outp;
        for (int r = 0; r < 4; r++) O[(size_t)(gr0 + r) * DM + gc] = f2bf(val[r]);
      } else {
        // V transposed: Vt[((b*16+h)*64+d)*2048 + s]
        unsigned short* O = (unsigned short*)Outp;
        int hh = gc >> 6, dd = gc & 63;
        int bidx = gr0 >> 11, srow = gr0 & 2047;
        uint2 pk;
        pk.x = (unsigned)f2bf(val[0]) | ((unsigned)f2bf(val[1]) << 16);
        pk.y = (unsigned)f2bf(val[2]) | ((unsigned)f2bf(val[3]) << 16);
        *(uint2*)&O[((size_t)(bidx * 16 + hh) * 64 + dd) * SQL + srow] = pk;
      }
    }
}

// ---------------- flash attention: Qb,Kb row-major bf16 [8192][1024]; Vt [b,h,64,2048] bf16
// block = (q-tile of 128 rows) x (b,h). 4 waves, each owns 32 q-rows x all kv.
__global__ __launch_bounds__(256) void attn_kernel(
    const unsigned short* __restrict__ Qb, const unsigned short* __restrict__ Kb,
    const unsigned short* __restrict__ Vt, unsigned short* __restrict__ Cv) {
  __shared__ unsigned short lds_k[64 * 72];   // [kv=64][d=64] stride 72
  __shared__ unsigned short lds_v[64 * 72];   // [d=64][kv=64] stride 72
  __shared__ unsigned short lds_p[128 * 72];  // [qrow=128][kv=64] stride 72
  int tid = threadIdx.x;
  int wave = tid >> 6, lane = tid & 63;
  int quad = lane >> 4, c16 = lane & 15;
  int qt = blockIdx.x, bh = blockIdx.y;
  int b = bh >> 4, h = bh & 15;

  // Q fragments direct from global (A layout: m=lane&15, k=quad*8+j), Q pre-scaled by 0.125
  bf16x8 qf[2][2];
  for (int i = 0; i < 2; i++)
    for (int ks = 0; ks < 2; ks++) {
      int gr = b * SQL + qt * 128 + wave * 32 + i * 16 + c16;
      qf[i][ks] = *(const bf16x8*)&Qb[(size_t)gr * DM + h * 64 + ks * 32 + quad * 8];
    }

  const floatx4 fzero = {0.f, 0.f, 0.f, 0.f};
  floatx4 o[2][4];
  for (int i = 0; i < 2; i++)
    for (int jd = 0; jd < 4; jd++) o[i][jd] = fzero;
  float mrow[2][4], lrow[2][4];
  for (int i = 0; i < 2; i++)
    for (int r = 0; r < 4; r++) { mrow[i][r] = -1e30f; lrow[i][r] = 0.f; }

  for (int t0 = 0; t0 < SQL; t0 += 64) {
    // stage K tile [64][64] and Vt tile [64][64]
    for (int u = 0; u < 2; u++) {
      int idx = u * 256 + tid;
      int r = idx >> 3, c8 = idx & 7;
      *(uint4*)&lds_k[r * 72 + c8 * 8] =
          *(const uint4*)&Kb[(size_t)(b * SQL + t0 + r) * DM + h * 64 + c8 * 8];
    }
    for (int u = 0; u < 2; u++) {
      int idx = u * 256 + tid;
      int r = idx >> 3, c8 = idx & 7;
      *(uint4*)&lds_v[r * 72 + c8 * 8] =
          *(const uint4*)&Vt[(size_t)(bh * 64 + r) * SQL + t0 + c8 * 8];
    }
    __syncthreads();

    // S = Q K^T  (A=Q frags, B=K rows; D: row=qrow, col=kvrow)
    floatx4 s[2][4];
    for (int i = 0; i < 2; i++)
      for (int j = 0; j < 4; j++) s[i][j] = fzero;
    for (int ks = 0; ks < 2; ks++) {
      bf16x8 kf[4];
      for (int j = 0; j < 4; j++)
        kf[j] = *(const bf16x8*)&lds_k[(j * 16 + c16) * 72 + ks * 32 + quad * 8];
      for (int i = 0; i < 2; i++)
        for (int j = 0; j < 4; j++)
          s[i][j] = __builtin_amdgcn_mfma_f32_16x16x32_bf16(qf[i][ks], kf[j], s[i][j], 0, 0, 0);
    }

    // online softmax: rows quad*4+r (+16i+32*wave); reduce across quad's 16 lanes
    for (int i = 0; i < 2; i++)
      for (int r = 0; r < 4; r++) {
        float mx = s[i][0][r];
        for (int j = 1; j < 4; j++) mx = fmaxf(mx, s[i][j][r]);
        for (int d = 1; d < 16; d <<= 1) mx = fmaxf(mx, __shfl_xor(mx, d));
        float mnew = fmaxf(mrow[i][r], mx);
        float alpha = __expf(mrow[i][r] - mnew);
        mrow[i][r] = mnew;
        float sum = 0.f;
        for (int j = 0; j < 4; j++) {
          float p = __expf(s[i][j][r] - mnew);
          s[i][j][r] = p;
          sum += p;
        }
        for (int d = 1; d < 16; d <<= 1) sum += __shfl_xor(sum, d);
        lrow[i][r] = lrow[i][r] * alpha + sum;
        for (int jd = 0; jd < 4; jd++) o[i][jd][r] *= alpha;  // per-row rescale
      }

    // write P (C layout) -> LDS row-major [qrow][kv] for A-layout reads (same-wave region)
    for (int i = 0; i < 2; i++)
      for (int j = 0; j < 4; j++)
        for (int r = 0; r < 4; r++)
          lds_p[(wave * 32 + i * 16 + quad * 4 + r) * 72 + j * 16 + c16] = f2bf(s[i][j][r]);
    __syncthreads();

    // O += P V  (A=P rows from LDS, B=Vt rows)
    for (int ks = 0; ks < 2; ks++) {
      bf16x8 pf[2], vf[4];
      for (int i = 0; i < 2; i++)
        pf[i] = *(const bf16x8*)&lds_p[(wave * 32 + i * 16 + c16) * 72 + ks * 32 + quad * 8];
      for (int jd = 0; jd < 4; jd++)
        vf[jd] = *(const bf16x8*)&lds_v[(jd * 16 + c16) * 72 + ks * 32 + quad * 8];
      for (int i = 0; i < 2; i++)
        for (int jd = 0; jd < 4; jd++)
          o[i][jd] = __builtin_amdgcn_mfma_f32_16x16x32_bf16(pf[i], vf[jd], o[i][jd], 0, 0, 0);
    }
    __syncthreads();
  }

  // epilogue: Cv[s][h*64+d] = o / l
  for (int i = 0; i < 2; i++)
    for (int jd = 0; jd < 4; jd++)
      for (int r = 0; r < 4; r++) {
        float val = o[i][jd][r] / lrow[i][r];
        int gr = b * SQL + qt * 128 + wave * 32 + i * 16 + quad * 4 + r;
        Cv[(size_t)gr * DM + h * 64 + jd * 16 + c16] = f2bf(val);
      }
}

extern "C" void kernel_launch(void* const* d_in, const int* in_sizes, int n_in,
                              void* d_out, int out_size, void* d_ws, size_t ws_size,
                              hipStream_t stream) {
  const float* q  = (const float*)d_in[0];
  const float* k  = (const float*)d_in[1];
  const float* v  = (const float*)d_in[2];
  const float* wq = (const float*)d_in[3];
  const float* bq = (const float*)d_in[4];
  const float* wk = (const float*)d_in[5];
  const float* bk = (const float*)d_in[6];
  const float* wv = (const float*)d_in[7];
  const float* bv = (const float*)d_in[8];
  const float* wo = (const float*)d_in[9];
  const float* bo = (const float*)d_in[10];
  float* out = (float*)d_out;

  char* ws = (char*)d_ws;
  unsigned short* wqt = (unsigned short*)(ws + (size_t)0);
  unsigned short* wkt = (unsigned short*)(ws + ((size_t)2 << 20));
  unsigned short* wvt = (unsigned short*)(ws + ((size_t)4 << 20));
  unsigned short* wot = (unsigned short*)(ws + ((size_t)6 << 20));
  unsigned short* Qb  = (unsigned short*)(ws + ((size_t)8 << 20));
  unsigned short* Kb  = (unsigned short*)(ws + ((size_t)24 << 20));
  unsigned short* Vt  = (unsigned short*)(ws + ((size_t)40 << 20));
  unsigned short* Cv  = (unsigned short*)(ws + ((size_t)56 << 20));
  // total workspace use: 72 MiB

  dim3 blk(256);
  transpose_w_kernel<<<dim3(16, 16), blk, 0, stream>>>(wq, wqt);
  transpose_w_kernel<<<dim3(16, 16), blk, 0, stream>>>(wk, wkt);
  transpose_w_kernel<<<dim3(16, 16), blk, 0, stream>>>(wv, wvt);
  transpose_w_kernel<<<dim3(16, 16), blk, 0, stream>>>(wo, wot);
  gemm_kernel<1, 0><<<dim3(8, 64), blk, 0, stream>>>(q, wqt, bq, Qb, 0.125f);
  gemm_kernel<1, 0><<<dim3(8, 64), blk, 0, stream>>>(k, wkt, bk, Kb, 1.0f);
  gemm_kernel<1, 2><<<dim3(8, 64), blk, 0, stream>>>(v, wvt, bv, Vt, 1.0f);
  attn_kernel<<<dim3(16, 64), blk, 0, stream>>>(Qb, Kb, Vt, Cv);
  gemm_kernel<0, 1><<<dim3(8, 64), blk, 0, stream>>>(Cv, wot, bo, out, 1.0f);
}

// Round 2
// 418.492 us; speedup vs baseline: 1.4237x; 1.4237x over previous
//
#include <hip/hip_runtime.h>

// MultiheadAttention: B=4, S=2048, D_MODEL=1024, H=16, D_K=64, fp32 in/out.
// Pipeline (all bf16 MFMA 16x16x32, fp32 accum):
//   1. transpose_w x4: W[K][N] f32 -> Wt[N][K] bf16
//   2. gemm<1,0>: Q = (q@wq+bq)*0.125*log2e -> bf16 [8192][1024]   (exp2 softmax)
//   3. gemm<1,0>: K = k@wk+bk        -> bf16 [8192][1024]
//   4. gemm<1,2>: V = v@wv+bv        -> bf16 [b,h,d,s] with kv-axis bit-permuted
//      within each 64-block so S^T's C-layout registers ARE the PV B-fragment.
//   5. attn: flash online softmax on S^T; P stays in registers (no LDS roundtrip)
//   6. gemm<0,1>: out = Cv@wo+bo -> f32 d_out

#define DM 1024
#define SQL 2048

typedef __attribute__((ext_vector_type(4))) float floatx4;
typedef __attribute__((ext_vector_type(8))) __bf16 bf16x8;
typedef __attribute__((ext_vector_type(4))) unsigned int uintx4;

__device__ __forceinline__ unsigned short f2bf(float f) {
  unsigned int u = __float_as_uint(f);
  u += 0x7fffu + ((u >> 16) & 1u);   // RNE
  return (unsigned short)(u >> 16);
}

// pack two f32 -> bf16 pair (round-half-up; inputs finite)
__device__ __forceinline__ unsigned int pack_bf(float lo, float hi) {
  unsigned int ulo = (__float_as_uint(lo) + 0x8000u) >> 16;
  unsigned int uhi = (__float_as_uint(hi) + 0x8000u) & 0xffff0000u;
  return ulo | uhi;
}

// ---------------- weight transpose: W[1024][1024] f32 -> Wt[1024][1024] bf16 (Wt[n][k]=W[k][n])
__global__ __launch_bounds__(256) void transpose_w_kernel(
    const float* __restrict__ W, unsigned short* __restrict__ Wt) {
  __shared__ unsigned short t[64][65];
  int tid = threadIdx.x;
  int n0 = blockIdx.x * 64, k0 = blockIdx.y * 64;
  for (int u = 0; u < 16; u++) {
    int idx = u * 256 + tid;
    int k = idx >> 6, n = idx & 63;
    t[k][n] = f2bf(W[(size_t)(k0 + k) * DM + n0 + n]);
  }
  __syncthreads();
  for (int u = 0; u < 16; u++) {
    int idx = u * 256 + tid;
    int n = idx >> 6, k = idx & 63;
    Wt[(size_t)(n0 + n) * DM + k0 + k] = t[k][n];
  }
}

// ---------------- GEMM: Out[8192][1024] = A[8192][1024] @ Wt^T + bias, tile 128x128, BK=64
// A_F32: A is f32 (else bf16). OUT_MODE: 0=bf16 row-major, 1=f32 row-major,
// 2=bf16 V-transposed [b,h,d,s] with s bit-permuted within 64-blocks.
template <int A_F32, int OUT_MODE>
__global__ __launch_bounds__(256) void gemm_kernel(
    const void* __restrict__ Ap, const unsigned short* __restrict__ Bt,
    const float* __restrict__ bias, void* __restrict__ Outp, float out_scale) {
  __shared__ unsigned short lds_a[128 * 72];  // [128][64] data, stride 72
  __shared__ unsigned short lds_b[128 * 72];
  int tid = threadIdx.x;
  int wave = tid >> 6, lane = tid & 63;
  int quad = lane >> 4, c16 = lane & 15;
  int wm = wave & 1, wn = wave >> 1;
  int m0 = blockIdx.y * 128, n0 = blockIdx.x * 128;

  floatx4 acc[4][4];
  const floatx4 fzero = {0.f, 0.f, 0.f, 0.f};
  for (int i = 0; i < 4; i++)
    for (int j = 0; j < 4; j++) acc[i][j] = fzero;

  for (int kt = 0; kt < DM; kt += 64) {
    if (A_F32) {
      const float* A = (const float*)Ap;
      for (int u = 0; u < 8; u++) {
        int idx = u * 256 + tid;
        int r = idx >> 4, c4 = idx & 15;
        float4 v = *(const float4*)&A[(size_t)(m0 + r) * DM + kt + c4 * 4];
        uint2 pk;
        pk.x = (unsigned)f2bf(v.x) | ((unsigned)f2bf(v.y) << 16);
        pk.y = (unsigned)f2bf(v.z) | ((unsigned)f2bf(v.w) << 16);
        *(uint2*)&lds_a[r * 72 + c4 * 4] = pk;
      }
    } else {
      const unsigned short* A = (const unsigned short*)Ap;
      for (int u = 0; u < 4; u++) {
        int idx = u * 256 + tid;
        int r = idx >> 3, c8 = idx & 7;
        *(uint4*)&lds_a[r * 72 + c8 * 8] =
            *(const uint4*)&A[(size_t)(m0 + r) * DM + kt + c8 * 8];
      }
    }
    for (int u = 0; u < 4; u++) {
      int idx = u * 256 + tid;
      int r = idx >> 3, c8 = idx & 7;
      *(uint4*)&lds_b[r * 72 + c8 * 8] =
          *(const uint4*)&Bt[(size_t)(n0 + r) * DM + kt + c8 * 8];
    }
    __syncthreads();
    for (int ks = 0; ks < 2; ks++) {
      bf16x8 af[4], bfr[4];
      for (int i = 0; i < 4; i++)
        af[i] = *(const bf16x8*)&lds_a[(wm * 64 + i * 16 + c16) * 72 + ks * 32 + quad * 8];
      for (int j = 0; j < 4; j++)
        bfr[j] = *(const bf16x8*)&lds_b[(wn * 64 + j * 16 + c16) * 72 + ks * 32 + quad * 8];
      for (int i = 0; i < 4; i++)
        for (int j = 0; j < 4; j++)
          acc[i][j] = __builtin_amdgcn_mfma_f32_16x16x32_bf16(af[i], bfr[j], acc[i][j], 0, 0, 0);
    }
    __syncthreads();
  }

  // epilogue: C/D layout row=(lane>>4)*4+reg, col=lane&15
  for (int i = 0; i < 4; i++)
    for (int j = 0; j < 4; j++) {
      int gc = n0 + wn * 64 + j * 16 + c16;
      float bv = bias[gc];
      float val[4];
      for (int r = 0; r < 4; r++) val[r] = (acc[i][j][r] + bv) * out_scale;
      int gr0 = m0 + wm * 64 + i * 16 + quad * 4;
      if (OUT_MODE == 1) {
        float* O = (float*)Outp;
        for (int r = 0; r < 4; r++) O[(size_t)(gr0 + r) * DM + gc] = val[r];
      } else if (OUT_MODE == 0) {
        unsigned short* O = (unsigned short*)Outp;
        for (int r = 0; r < 4; r++) O[(size_t)(gr0 + r) * DM + gc] = f2bf(val[r]);
      } else {
        // V transposed + kv-permuted: store s at column c where
        // c = (s5, s3, s2, s4, s1, s0)  [bits] within each 64-block.
        unsigned short* O = (unsigned short*)Outp;
        int hh = gc >> 6, dd = gc & 63;
        int bidx = gr0 >> 11, srow = gr0 & 2047;
        int s6 = srow & 63;   // low 2 bits are 0 (gr0 multiple of 4)
        int c6 = (s6 & 32) | ((s6 & 8) << 1) | ((s6 & 4) << 1) | ((s6 & 16) >> 2) | (s6 & 3);
        int srowp = (srow & ~63) | c6;
        uint2 pk;
        pk.x = (unsigned)f2bf(val[0]) | ((unsigned)f2bf(val[1]) << 16);
        pk.y = (unsigned)f2bf(val[2]) | ((unsigned)f2bf(val[3]) << 16);
        *(uint2*)&O[((size_t)(bidx * 16 + hh) * 64 + dd) * SQL + srowp] = pk;
      }
    }
}

// ---------------- flash attention, S^T formulation.
// Qb,Kb row-major bf16 [8192][1024] (Q pre-scaled by 0.125*log2e); Vt [b,h,64,2048] kv-permuted.
// Block = (q-tile of 128) x (b,h); 4 waves; wave owns 32 q (n-dim) x all kv.
// S^T = mfma(A=K-rows, B=Q-rows): C layout -> q on lane&15, kv on quad*4+reg.
// Softmax: within-lane reduce over 16 kv + 2 cross-quad shfl_xor.
// PV: O^T[d][q] = mfma(A=Vt-rows, B=P^T); V's kv permutation makes the packed
// S^T registers exactly the B-fragment (verified bit-match: lds_v column
// c=(ks,q',j) holds kv=32ks+16(j>>2)+4q'+2((j>>1)&1)+(j&1), which is reg
// pair (j>>1)&1, element j&1 of S^T tile 2ks+(j>>2) in lane (q', c16)).
__global__ __launch_bounds__(256) void attn_kernel(
    const unsigned short* __restrict__ Qb, const unsigned short* __restrict__ Kb,
    const unsigned short* __restrict__ Vt, unsigned short* __restrict__ Cv) {
  __shared__ unsigned short lds_k[64 * 72];   // [kv=64][d=64] stride 72
  __shared__ unsigned short lds_v[64 * 72];   // [d=64][kv=64 permuted] stride 72
  int tid = threadIdx.x;
  int wave = tid >> 6, lane = tid & 63;
  int quad = lane >> 4, c16 = lane & 15;
  int qt = blockIdx.x, bh = blockIdx.y;
  int b = bh >> 4, h = bh & 15;

  // Q fragments (B operand): B[n=q][k=d], q = wave*32 + i*16 + c16, d = ks*32+quad*8+j
  bf16x8 qf[2][2];
  for (int i = 0; i < 2; i++)
    for (int ks = 0; ks < 2; ks++) {
      int gr = b * SQL + qt * 128 + wave * 32 + i * 16 + c16;
      qf[i][ks] = *(const bf16x8*)&Qb[(size_t)gr * DM + h * 64 + ks * 32 + quad * 8];
    }

  const floatx4 fzero = {0.f, 0.f, 0.f, 0.f};
  floatx4 acc[4][2];  // O^T: [d-tile dt][q-tile i]; elem: d=16dt+4quad+r, q=wave*32+16i+c16
  for (int dt = 0; dt < 4; dt++)
    for (int i = 0; i < 2; i++) acc[dt][i] = fzero;
  float m_[2] = {-1e30f, -1e30f};
  float l_[2] = {0.f, 0.f};

  for (int t0 = 0; t0 < SQL; t0 += 64) {
    // stage K tile [kv][d] and Vt tile [d][kv-permuted]
    for (int u = 0; u < 2; u++) {
      int idx = u * 256 + tid;
      int r = idx >> 3, c8 = idx & 7;
      *(uint4*)&lds_k[r * 72 + c8 * 8] =
          *(const uint4*)&Kb[(size_t)(b * SQL + t0 + r) * DM + h * 64 + c8 * 8];
      *(uint4*)&lds_v[r * 72 + c8 * 8] =
          *(const uint4*)&Vt[(size_t)(bh * 64 + r) * SQL + t0 + c8 * 8];
    }
    __syncthreads();

    // S^T = K Q^T: A=K rows (m=kv), B=Q rows (n=q). s[i][jt]: kv=16jt+4quad+r, q=16i+c16(+wave*32)
    floatx4 s[2][4];
    for (int i = 0; i < 2; i++)
      for (int jt = 0; jt < 4; jt++) s[i][jt] = fzero;
    for (int ks = 0; ks < 2; ks++) {
      bf16x8 kf[4];
      for (int jt = 0; jt < 4; jt++)
        kf[jt] = *(const bf16x8*)&lds_k[(jt * 16 + c16) * 72 + ks * 32 + quad * 8];
      for (int i = 0; i < 2; i++)
        for (int jt = 0; jt < 4; jt++)
          s[i][jt] = __builtin_amdgcn_mfma_f32_16x16x32_bf16(kf[jt], qf[i][ks], s[i][jt], 0, 0, 0);
    }

    // online softmax (exp2 domain; log2e folded into Q scale) + pack P^T to bf16
    unsigned int pk[2][8];  // [i][jt*2+pi]; frag for PV step ks = dwords [4ks..4ks+3]
    for (int i = 0; i < 2; i++) {
      float mx = s[i][0][0];
      for (int jt = 0; jt < 4; jt++)
        for (int r = 0; r < 4; r++) mx = fmaxf(mx, s[i][jt][r]);
      mx = fmaxf(mx, __shfl_xor(mx, 16));
      mx = fmaxf(mx, __shfl_xor(mx, 32));
      float mnew = fmaxf(m_[i], mx);
      float alpha = __builtin_amdgcn_exp2f(m_[i] - mnew);
      m_[i] = mnew;
      float sum = 0.f;
      for (int jt = 0; jt < 4; jt++)
        for (int r = 0; r < 4; r++) {
          float p = __builtin_amdgcn_exp2f(s[i][jt][r] - mnew);
          s[i][jt][r] = p;
          sum += p;
        }
      sum += __shfl_xor(sum, 16);
      sum += __shfl_xor(sum, 32);
      l_[i] = l_[i] * alpha + sum;
      for (int dt = 0; dt < 4; dt++) acc[dt][i] *= alpha;
      for (int jt = 0; jt < 4; jt++) {
        pk[i][jt * 2 + 0] = pack_bf(s[i][jt][0], s[i][jt][1]);
        pk[i][jt * 2 + 1] = pack_bf(s[i][jt][2], s[i][jt][3]);
      }
    }

    // O^T += V^T P^T: A=Vt rows (m=d), B=P^T straight from pk registers
    for (int ks = 0; ks < 2; ks++) {
      bf16x8 pf[2];
      for (int i = 0; i < 2; i++) {
        uintx4 pw;
        pw.x = pk[i][4 * ks + 0];
        pw.y = pk[i][4 * ks + 1];
        pw.z = pk[i][4 * ks + 2];
        pw.w = pk[i][4 * ks + 3];
        pf[i] = __builtin_bit_cast(bf16x8, pw);
      }
      for (int dt = 0; dt < 4; dt++) {
        bf16x8 av = *(const bf16x8*)&lds_v[(dt * 16 + c16) * 72 + ks * 32 + quad * 8];
        for (int i = 0; i < 2; i++)
          acc[dt][i] = __builtin_amdgcn_mfma_f32_16x16x32_bf16(av, pf[i], acc[dt][i], 0, 0, 0);
      }
    }
    __syncthreads();
  }

  // epilogue: O^T[d][q] -> Cv[s=q][h*64+d], divide by l
  for (int i = 0; i < 2; i++) {
    float inv = 1.f / l_[i];
    int gr = b * SQL + qt * 128 + wave * 32 + i * 16 + c16;
    for (int dt = 0; dt < 4; dt++) {
      uint2 pkw;
      pkw.x = (unsigned)f2bf(acc[dt][i][0] * inv) | ((unsigned)f2bf(acc[dt][i][1] * inv) << 16);
      pkw.y = (unsigned)f2bf(acc[dt][i][2] * inv) | ((unsigned)f2bf(acc[dt][i][3] * inv) << 16);
      *(uint2*)&Cv[(size_t)gr * DM + h * 64 + dt * 16 + quad * 4] = pkw;
    }
  }
}

extern "C" void kernel_launch(void* const* d_in, const int* in_sizes, int n_in,
                              void* d_out, int out_size, void* d_ws, size_t ws_size,
                              hipStream_t stream) {
  const float* q  = (const float*)d_in[0];
  const float* k  = (const float*)d_in[1];
  const float* v  = (const float*)d_in[2];
  const float* wq = (const float*)d_in[3];
  const float* bq = (const float*)d_in[4];
  const float* wk = (const float*)d_in[5];
  const float* bk = (const float*)d_in[6];
  const float* wv = (const float*)d_in[7];
  const float* bv = (const float*)d_in[8];
  const float* wo = (const float*)d_in[9];
  const float* bo = (const float*)d_in[10];
  float* out = (float*)d_out;

  char* ws = (char*)d_ws;
  unsigned short* wqt = (unsigned short*)(ws + (size_t)0);
  unsigned short* wkt = (unsigned short*)(ws + ((size_t)2 << 20));
  unsigned short* wvt = (unsigned short*)(ws + ((size_t)4 << 20));
  unsigned short* wot = (unsigned short*)(ws + ((size_t)6 << 20));
  unsigned short* Qb  = (unsigned short*)(ws + ((size_t)8 << 20));
  unsigned short* Kb  = (unsigned short*)(ws + ((size_t)24 << 20));
  unsigned short* Vt  = (unsigned short*)(ws + ((size_t)40 << 20));
  unsigned short* Cv  = (unsigned short*)(ws + ((size_t)56 << 20));

  const float QSCALE = 0.125f * 1.44269504088896340736f;  // 1/sqrt(64) * log2(e)

  dim3 blk(256);
  transpose_w_kernel<<<dim3(16, 16), blk, 0, stream>>>(wq, wqt);
  transpose_w_kernel<<<dim3(16, 16), blk, 0, stream>>>(wk, wkt);
  transpose_w_kernel<<<dim3(16, 16), blk, 0, stream>>>(wv, wvt);
  transpose_w_kernel<<<dim3(16, 16), blk, 0, stream>>>(wo, wot);
  gemm_kernel<1, 0><<<dim3(8, 64), blk, 0, stream>>>(q, wqt, bq, Qb, QSCALE);
  gemm_kernel<1, 0><<<dim3(8, 64), blk, 0, stream>>>(k, wkt, bk, Kb, 1.0f);
  gemm_kernel<1, 2><<<dim3(8, 64), blk, 0, stream>>>(v, wvt, bv, Vt, 1.0f);
  attn_kernel<<<dim3(16, 64), blk, 0, stream>>>(Qb, Kb, Vt, Cv);
  gemm_kernel<0, 1><<<dim3(8, 64), blk, 0, stream>>>(Cv, wot, bo, out, 1.0f);
}